// Round 1
// baseline (453.122 us; speedup 1.0000x reference)
//
#include <hip/hip_runtime.h>

// EoMT criterion: cost matrix + Hungarian (JV) + losses, fully on-device.
// Shapes fixed per setup_inputs(): bs=2, N=100, C+1=7, H=W=512, M=20.

typedef unsigned int u32;

#define BS 2
#define NQ 100
#define C1 7
#define HWPX 262144     // 512*512
#define MG 20
#define NO_OBJ_C 6

// ---- workspace layout (bytes) ----
static constexpr size_t OFF_PACKED = 0;                                   // u32 [BS][HWPX]
static constexpr size_t OFF_X      = OFF_PACKED + (size_t)BS*HWPX*4;      // f32 [BS][NQ][MG]  Sum_{y=1} x
static constexpr size_t OFF_S      = OFF_X      + (size_t)BS*NQ*MG*4;     // f32 [BS][NQ][MG]  Sum_{y=1} p
static constexpr size_t OFF_LQS    = OFF_S      + (size_t)BS*NQ*MG*4;     // f32 [BS][NQ]      Sum log(1-p)
static constexpr size_t OFF_PSUM   = OFF_LQS    + (size_t)BS*NQ*4;        // f32 [BS][NQ]      Sum p
static constexpr size_t OFF_YSUM   = OFF_PSUM   + (size_t)BS*NQ*4;        // f32 [BS][MG]
static constexpr size_t OFF_COST   = OFF_YSUM   + (size_t)BS*MG*4;        // f32 [BS][NQ][MG]
static constexpr size_t OFF_MATCH  = OFF_COST   + (size_t)BS*NQ*MG*4;     // i32 [BS][MG]  gt -> pred
static constexpr size_t ZERO_BYTES = OFF_YSUM - OFF_X;                    // accumulators to zero each call

__device__ __forceinline__ float fast_rcp(float x){
#if __has_builtin(__builtin_amdgcn_rcpf)
    return __builtin_amdgcn_rcpf(x);
#else
    return 1.0f / x;
#endif
}

// ---- pack 20 binary masks into one u32 per pixel ----
__global__ __launch_bounds__(256) void k_pack(const int* __restrict__ gt, u32* __restrict__ packed){
    int i = blockIdx.x * 256 + threadIdx.x;       // 0 .. BS*HWPX-1
    int b = i >> 18;                              // /HWPX
    int pix = i & (HWPX - 1);
    const int* g = gt + (size_t)b * MG * HWPX + pix;
    u32 w = 0;
#pragma unroll
    for (int m = 0; m < MG; m++) w |= ((u32)g[(size_t)m * HWPX] & 1u) << m;
    packed[i] = w;
}

// ---- ysum[b][m] = popcount of mask m ----
__global__ __launch_bounds__(256) void k_ysum(const u32* __restrict__ packed, float* __restrict__ ysum){
    int b = blockIdx.x / MG, m = blockIdx.x % MG;
    const u32* pk = packed + (size_t)b * HWPX;
    int cnt = 0;
    for (int i = threadIdx.x; i < HWPX; i += 256) cnt += (int)((pk[i] >> m) & 1u);
#pragma unroll
    for (int off = 32; off; off >>= 1) cnt += __shfl_xor(cnt, off);
    __shared__ int wred[4];
    if ((threadIdx.x & 63) == 0) wred[threadIdx.x >> 6] = cnt;
    __syncthreads();
    if (threadIdx.x == 0) ysum[blockIdx.x] = (float)(wred[0] + wred[1] + wred[2] + wred[3]);
}

// ---- heavy kernel: per (b,n): X[m], S[m], lqsum, psum ----
__global__ __launch_bounds__(256) void k_main(const float* __restrict__ mlog, const u32* __restrict__ packed,
                                              float* __restrict__ Xg, float* __restrict__ Sg,
                                              float* __restrict__ lqsg, float* __restrict__ psg){
    int blk = blockIdx.x;            // [BS*NQ*4]
    int chunk = blk & 3;
    int bn = blk >> 2;               // b*NQ + n
    int b = bn / NQ;
    const float4* src4 = (const float4*)(mlog + (size_t)bn * HWPX + (size_t)chunk * (HWPX / 4));
    const uint4*  pk4  = (const uint4*)(packed + (size_t)b * HWPX + (size_t)chunk * (HWPX / 4));
    int t = threadIdx.x;

    float xacc[MG], sacc[MG];
#pragma unroll
    for (int m = 0; m < MG; m++){ xacc[m] = 0.f; sacc[m] = 0.f; }
    float lq_acc = 0.f, p_acc = 0.f;

    for (int it = 0; it < (HWPX / 4) / (256 * 4); ++it){   // 64 iters
        int idx = it * 256 + t;
        float4 xv = src4[idx];
        uint4  wv = pk4[idx];
        float xa[4] = {xv.x, xv.y, xv.z, xv.w};
        u32   wa[4] = {wv.x, wv.y, wv.z, wv.w};
#pragma unroll
        for (int c = 0; c < 4; c++){
            float x = xa[c];
            u32   w = wa[c];
            float e = __expf(-x);
            float p = fast_rcp(1.0f + e);          // sigmoid(x)
            float lq = -__logf(1.0f + e) - x;      // log(1 - sigmoid(x))
            p_acc  += p;
            lq_acc += lq;
#pragma unroll
            for (int m = 0; m < MG; m++){
                float bf = (float)((w >> m) & 1u);
                xacc[m] = fmaf(x, bf, xacc[m]);
                sacc[m] = fmaf(p, bf, sacc[m]);
            }
        }
    }
    // wave reduction then one atomic per wave
#pragma unroll
    for (int m = 0; m < MG; m++){
#pragma unroll
        for (int off = 32; off; off >>= 1){
            xacc[m] += __shfl_xor(xacc[m], off);
            sacc[m] += __shfl_xor(sacc[m], off);
        }
    }
#pragma unroll
    for (int off = 32; off; off >>= 1){
        lq_acc += __shfl_xor(lq_acc, off);
        p_acc  += __shfl_xor(p_acc, off);
    }
    if ((t & 63) == 0){
#pragma unroll
        for (int m = 0; m < MG; m++){
            atomicAdd(&Xg[bn * MG + m], xacc[m]);
            atomicAdd(&Sg[bn * MG + m], sacc[m]);
        }
        atomicAdd(&lqsg[bn], lq_acc);
        atomicAdd(&psg[bn], p_acc);
    }
}

// ---- cost matrix ----
__global__ __launch_bounds__(128) void k_cost(const float* __restrict__ cl, const int* __restrict__ gtc,
                                              const float* __restrict__ Xg, const float* __restrict__ Sg,
                                              const float* __restrict__ lqsg, const float* __restrict__ psg,
                                              const float* __restrict__ ysum, float* __restrict__ cost){
    int b = blockIdx.x;
    int n = threadIdx.x;
    if (n >= NQ) return;
    const float* lg = cl + ((size_t)b * NQ + n) * C1;
    float l0=lg[0],l1=lg[1],l2=lg[2],l3=lg[3],l4=lg[4],l5=lg[5],l6=lg[6];
    float mx = fmaxf(fmaxf(fmaxf(l0,l1),fmaxf(l2,l3)), fmaxf(fmaxf(l4,l5),l6));
    float e0=__expf(l0-mx),e1=__expf(l1-mx),e2=__expf(l2-mx),e3=__expf(l3-mx),
          e4=__expf(l4-mx),e5=__expf(l5-mx),e6=__expf(l6-mx);
    float inv = 1.0f / (e0+e1+e2+e3+e4+e5+e6);
    float lqv = lqsg[b*NQ+n], psv = psg[b*NQ+n];
    for (int m = 0; m < MG; m++){
        int c = gtc[b*MG+m];   // 0..5
        float ec = (c==0)?e0:(c==1)?e1:(c==2)?e2:(c==3)?e3:(c==4)?e4:e5;
        float cc = -ec * inv;
        int nm = (b*NQ+n)*MG + m;
        float bce = -(Xg[nm] + lqv) * (1.0f / (float)HWPX);
        float dice = 1.0f - (2.0f*Sg[nm] + 1.0f) / (psv + ysum[b*MG+m] + 1.0f);
        cost[nm] = 2.0f*cc + 5.0f*bce + 5.0f*dice;
    }
}

// ---- Hungarian (Jonker-Volgenant), faithful port of the reference on cost^T [20 x 100] ----
// One 64-lane wave per batch image; columns are lane-parallel; f64 like the reference.
__global__ __launch_bounds__(64) void k_hung(const float* __restrict__ cost, int* __restrict__ match){
    __shared__ double c[MG][NQ];
    __shared__ double u[MG + 1];
    __shared__ double v[NQ + 1];
    __shared__ double minv[NQ + 1];
    __shared__ int p[NQ + 1];
    __shared__ int way[NQ + 1];
    __shared__ int used[NQ + 1];
    int b = blockIdx.x, t = threadIdx.x;

    for (int idx = t; idx < MG * NQ; idx += 64){
        int i = idx / NQ, j = idx % NQ;
        c[i][j] = (double)cost[((size_t)b * NQ + j) * MG + i];   // transposed
    }
    for (int j = t; j <= NQ; j += 64){ v[j] = 0.0; p[j] = 0; way[j] = 0; }
    if (t <= MG) u[t] = 0.0;
    __syncthreads();

    const double INF = 1e18;
    for (int i = 1; i <= MG; i++){
        if (t == 0) p[0] = i;
        for (int j = t; j <= NQ; j += 64){ minv[j] = INF; used[j] = 0; }
        __syncthreads();
        int j0 = 0;
        while (true){
            if (t == 0) used[j0] = 1;
            __syncthreads();
            int i0 = p[j0];
            double du = u[i0];
            for (int j = t + 1; j <= NQ; j += 64){          // j in 1..100
                if (!used[j]){
                    double cand = c[i0 - 1][j - 1] - du - v[j];
                    if (cand < minv[j]){ minv[j] = cand; way[j] = j0; }
                }
            }
            __syncthreads();
            // argmin over unused (first-index tie-break, like np.argmin)
            double best = INF; int bj = NQ + 1;
            for (int j = t + 1; j <= NQ; j += 64){
                double mv = used[j] ? INF : minv[j];
                if (mv < best || (mv == best && j < bj)){ best = mv; bj = j; }
            }
#pragma unroll
            for (int off = 32; off; off >>= 1){
                double ob = __shfl_xor(best, off);
                int    oj = __shfl_xor(bj, off);
                if (ob < best || (ob == best && oj < bj)){ best = ob; bj = oj; }
            }
            int j1 = bj;
            double delta = best;
            for (int j = t; j <= NQ; j += 64){              // includes j=0
                if (used[j]){
                    u[p[j]] += delta;    // p[] distinct over used cols -> race-free
                    v[j] -= delta;
                } else {
                    minv[j] -= delta;
                }
            }
            __syncthreads();
            j0 = j1;
            if (p[j0] == 0) break;
        }
        if (t == 0){
            int jj = j0;
            while (jj){ int jn = way[jj]; p[jj] = p[jn]; jj = jn; }
        }
        __syncthreads();
    }
    for (int j = t + 1; j <= NQ; j += 64){
        if (p[j] != 0) match[b * MG + (p[j] - 1)] = j - 1;   // gt index -> pred index
    }
}

// ---- final losses ----
__global__ __launch_bounds__(256) void k_final(const float* __restrict__ cl, const int* __restrict__ gtc,
                                               const float* __restrict__ Xg, const float* __restrict__ Sg,
                                               const float* __restrict__ lqsg, const float* __restrict__ psg,
                                               const float* __restrict__ ysum, const int* __restrict__ match,
                                               float* __restrict__ out){
    __shared__ int target[BS * NQ];
    __shared__ float acc[BS][4];   // {w*nll sum, w sum, bce sum, dice sum}
    int t = threadIdx.x;
    if (t < BS * 4) acc[t >> 2][t & 3] = 0.0f;
    if (t < BS * NQ) target[t] = NO_OBJ_C;
    __syncthreads();
    if (t < BS * MG){
        int b = t / MG;
        target[b * NQ + match[t]] = gtc[t];
    }
    __syncthreads();
    if (t < BS * NQ){
        int b = t / NQ;
        const float* lg = cl + (size_t)t * C1;
        float l0=lg[0],l1=lg[1],l2=lg[2],l3=lg[3],l4=lg[4],l5=lg[5],l6=lg[6];
        float mx = fmaxf(fmaxf(fmaxf(l0,l1),fmaxf(l2,l3)), fmaxf(fmaxf(l4,l5),l6));
        float se = __expf(l0-mx)+__expf(l1-mx)+__expf(l2-mx)+__expf(l3-mx)
                 + __expf(l4-mx)+__expf(l5-mx)+__expf(l6-mx);
        float lse = __logf(se) + mx;
        int tg = target[t];
        float lt = (tg==0)?l0:(tg==1)?l1:(tg==2)?l2:(tg==3)?l3:(tg==4)?l4:(tg==5)?l5:l6;
        float nll = lse - lt;
        float w = (tg == NO_OBJ_C) ? 0.1f : 1.0f;
        atomicAdd(&acc[b][0], w * nll);
        atomicAdd(&acc[b][1], w);
    }
    if (t < BS * MG){
        int b = t / MG, k = t % MG;
        int pr = match[t];
        int nm = (b * NQ + pr) * MG + k;
        float bk = -(Xg[nm] + lqsg[b * NQ + pr]);   // sum over HW of -[y logp + (1-y) log(1-p)]
        float dk = 1.0f - (2.0f * Sg[nm] + 1.0f) / (psg[b * NQ + pr] + ysum[t] + 1.0f);
        atomicAdd(&acc[b][2], bk);
        atomicAdd(&acc[b][3], dk);
    }
    __syncthreads();
    if (t == 0){
        float tc = 0.f, tm = 0.f, td = 0.f;
        for (int b = 0; b < BS; b++){
            tc += acc[b][0] / acc[b][1];
            tm += acc[b][2] / ((float)MG * (float)HWPX);
            td += acc[b][3] / (float)MG;
        }
        tc *= 0.5f; tm *= 0.5f; td *= 0.5f;
        out[0] = tc; out[1] = tm; out[2] = td;
        out[3] = 2.0f * tc + 5.0f * tm + 5.0f * td;
    }
}

extern "C" void kernel_launch(void* const* d_in, const int* in_sizes, int n_in,
                              void* d_out, int out_size, void* d_ws, size_t ws_size,
                              hipStream_t stream){
    const float* cls_logits  = (const float*)d_in[0];
    const float* mask_logits = (const float*)d_in[1];
    const int*   gt_classes  = (const int*)d_in[2];
    const int*   gt_masks    = (const int*)d_in[3];
    float* out = (float*)d_out;
    char* ws = (char*)d_ws;

    u32*   packed = (u32*)  (ws + OFF_PACKED);
    float* Xg     = (float*)(ws + OFF_X);
    float* Sg     = (float*)(ws + OFF_S);
    float* lqs    = (float*)(ws + OFF_LQS);
    float* ps     = (float*)(ws + OFF_PSUM);
    float* ysum   = (float*)(ws + OFF_YSUM);
    float* cost   = (float*)(ws + OFF_COST);
    int*   match  = (int*)  (ws + OFF_MATCH);

    hipMemsetAsync(ws + OFF_X, 0, ZERO_BYTES, stream);
    hipLaunchKernelGGL(k_pack,  dim3(BS * HWPX / 256), dim3(256), 0, stream, gt_masks, packed);
    hipLaunchKernelGGL(k_ysum,  dim3(BS * MG),         dim3(256), 0, stream, packed, ysum);
    hipLaunchKernelGGL(k_main,  dim3(BS * NQ * 4),     dim3(256), 0, stream, mask_logits, packed, Xg, Sg, lqs, ps);
    hipLaunchKernelGGL(k_cost,  dim3(BS),              dim3(128), 0, stream, cls_logits, gt_classes, Xg, Sg, lqs, ps, ysum, cost);
    hipLaunchKernelGGL(k_hung,  dim3(BS),              dim3(64),  0, stream, cost, match);
    hipLaunchKernelGGL(k_final, dim3(1),               dim3(256), 0, stream, cls_logits, gt_classes, Xg, Sg, lqs, ps, ysum, match, out);
}

// Round 3
// 171.031 us; speedup vs baseline: 2.6494x; 2.6494x over previous
//
#include <hip/hip_runtime.h>

// EoMT criterion v2.1: MFMA-based mask reductions + fused cost/Hungarian/losses.
// Shapes fixed: bs=2, N=100, C+1=7, H=W=512 (HW=262144), M=20.

typedef unsigned int u32;
typedef __attribute__((ext_vector_type(8))) short short8;   // 8 bf16 (4 VGPRs)
typedef __attribute__((ext_vector_type(4))) float f32x4;

#define BS 2
#define NQ 100
#define C1 7
#define HWPX 262144
#define MG 20
#define NO_OBJ_C 6
#define NROWS 112            // 7 tiles of 16: rows 0-99 real, 100-111 = ones rows (row100 -> ysum)
#define NT 7
#define CHUNK 2048           // pixels per block
#define NCHUNK (HWPX / CHUNK)   // 128
#define WSUB (CHUNK / 4)     // 512 px per wave
#define KSTEPS (WSUB / 32)   // 16

// ---- workspace layout (bytes) ----
static constexpr size_t OFF_PACKED = 0;                                 // u32 [BS][HWPX] = 2MB
static constexpr size_t OFF_X      = (size_t)BS * HWPX * 4;             // f32 [BS][112][32]
static constexpr size_t OFF_S      = OFF_X + (size_t)BS * NROWS * 32 * 4;
static constexpr size_t OFF_LQS    = OFF_S + (size_t)BS * NROWS * 32 * 4; // f32 [BS][112]
static constexpr size_t ZERO_BYTES = (OFF_LQS + (size_t)BS * NROWS * 4) - OFF_X;

__device__ __forceinline__ float fast_rcp(float x){
#if __has_builtin(__builtin_amdgcn_rcpf)
    return __builtin_amdgcn_rcpf(x);
#else
    return 1.0f / x;
#endif
}

__device__ __forceinline__ short8 mk8(const u32 w[4]){
    union { u32 u[4]; short8 v; } c;
    c.u[0] = w[0]; c.u[1] = w[1]; c.u[2] = w[2]; c.u[3] = w[3];
    return c.v;
}

// f32 -> bf16 bits, round-to-nearest-even (inputs are finite; no NaN handling needed)
__device__ __forceinline__ u32 f2bf(float f){
    u32 u = __builtin_bit_cast(u32, f);
    return (u + 0x7FFFu + ((u >> 16) & 1u)) >> 16;
}
__device__ __forceinline__ u32 pkbf(float lo, float hi){
    return f2bf(lo) | (f2bf(hi) << 16);
}

// ---- pack 20 binary masks into one u32 per pixel (4 px/thread) + zero d_out ----
__global__ __launch_bounds__(256) void k_pack(const int* __restrict__ gt, u32* __restrict__ packed,
                                              float* __restrict__ out){
    if (blockIdx.x == 0 && threadIdx.x < 4) out[threadIdx.x] = 0.0f;
    int i4 = blockIdx.x * 256 + threadIdx.x;      // 0 .. BS*HWPX/4-1
    int base = i4 * 4;
    int b = base >> 18;
    int pix = base & (HWPX - 1);
    const int* g = gt + ((size_t)b * MG << 18) + pix;
    u32 w0 = 0, w1 = 0, w2 = 0, w3 = 0;
#pragma unroll
    for (int m = 0; m < MG; m++){
        int4 v = *(const int4*)(g + ((size_t)m << 18));
        w0 |= ((u32)v.x & 1u) << m;
        w1 |= ((u32)v.y & 1u) << m;
        w2 |= ((u32)v.z & 1u) << m;
        w3 |= ((u32)v.w & 1u) << m;
    }
    *(uint4*)(packed + ((size_t)b << 18) + pix) = make_uint4(w0, w1, w2, w3);
}

// ---- heavy kernel: X[n,m], S[n,m] via MFMA; lqsum via VALU; psum via ones-col; ysum via ones-rows ----
__global__ __launch_bounds__(256) void k_main(const float* __restrict__ mlog, const u32* __restrict__ pkd,
                                              float* __restrict__ Xg, float* __restrict__ Sg,
                                              float* __restrict__ lqs){
    int blk = blockIdx.x;                 // [BS * NCHUNK * NT]
    int tile = blk % NT;
    int rest = blk / NT;
    int chunk = rest % NCHUNK;
    int b = rest / NCHUNK;
    int t = threadIdx.x;
    int wave = t >> 6, lane = t & 63;
    int lr = lane & 15;                   // A-row-in-tile / B-col
    int kq = lane >> 4;                   // k-quarter
    int row = tile * 16 + lr;             // global n row (0..111)
    bool real = row < NQ;
    int rowc = real ? row : (NQ - 1);

    const float* xrow = mlog + ((size_t)b * NQ + rowc) * HWPX;
    const u32* pk = pkd + ((size_t)b << 18);
    int pxbase = chunk * CHUNK + wave * WSUB + kq * 8;

    // B-expansion per-lane constants
    u32 bsel1 = 1u << lr;                               // tile1: mask bit lr
    u32 bsel2 = (lr < 4) ? (0x10000u << lr) : 0u;       // tile2: masks 16..19
    u32 bforce = (lr == 4) ? 0x3F80u : 0u;              // tile2 col 20 = ones

    f32x4 accX0 = {0,0,0,0}, accX1 = {0,0,0,0}, accS0 = {0,0,0,0}, accS1 = {0,0,0,0};
    float lqacc = 0.0f;

#pragma unroll 2
    for (int s = 0; s < KSTEPS; s++){
        int px = pxbase + s * 32;
        f32x4 xa = *(const f32x4*)(xrow + px);
        f32x4 xb = *(const f32x4*)(xrow + px + 4);
        uint4 wa = *(const uint4*)(pk + px);
        uint4 wb = *(const uint4*)(pk + px + 4);
        u32 w[8]  = {wa.x, wa.y, wa.z, wa.w, wb.x, wb.y, wb.z, wb.w};
        float x[8] = {xa[0], xa[1], xa[2], xa[3], xb[0], xb[1], xb[2], xb[3]};

        u32 axw[4], apw[4], b1w[4], b2w[4];
#pragma unroll
        for (int jj = 0; jj < 4; jj++){
            float x0 = x[2*jj], x1 = x[2*jj+1];
            float e0 = __expf(-x0), e1 = __expf(-x1);
            float d0 = 1.0f + e0,   d1 = 1.0f + e1;
            float p0 = fast_rcp(d0), p1 = fast_rcp(d1);
            float lq0 = -__logf(d0) - x0;      // log(1 - sigmoid(x))
            float lq1 = -__logf(d1) - x1;
            lqacc += lq0 + lq1;
            axw[jj] = pkbf(x0, x1);
            apw[jj] = pkbf(p0, p1);
            u32 wl = w[2*jj], wh = w[2*jj+1];
            u32 t1l = (wl & bsel1) ? 0x3F80u : 0u;
            u32 t1h = (wh & bsel1) ? 0x3F80u : 0u;
            u32 t2l = ((wl & bsel2) ? 0x3F80u : 0u) | bforce;
            u32 t2h = ((wh & bsel2) ? 0x3F80u : 0u) | bforce;
            b1w[jj] = t1l | (t1h << 16);
            b2w[jj] = t2l | (t2h << 16);
        }
        if (!real){
#pragma unroll
            for (int jj = 0; jj < 4; jj++){ axw[jj] = 0x3F803F80u; apw[jj] = 0x3F803F80u; }
        }
        short8 Ax = mk8(axw), Ap = mk8(apw), B0 = mk8(b1w), B1 = mk8(b2w);
        accX0 = __builtin_amdgcn_mfma_f32_16x16x32_bf16(Ax, B0, accX0, 0, 0, 0);
        accX1 = __builtin_amdgcn_mfma_f32_16x16x32_bf16(Ax, B1, accX1, 0, 0, 0);
        accS0 = __builtin_amdgcn_mfma_f32_16x16x32_bf16(Ap, B0, accS0, 0, 0, 0);
        accS1 = __builtin_amdgcn_mfma_f32_16x16x32_bf16(Ap, B1, accS1, 0, 0, 0);
    }

    // lq: rows live on lanes (lr, lr+16, lr+32, lr+48) -> combine quarters
    float lqv = lqacc + __shfl_xor(lqacc, 16);
    lqv += __shfl_xor(lqv, 32);

    __shared__ float red[2][16][32];
    __shared__ float redlq[16];
    for (int i = t; i < 2*16*32; i += 256) ((float*)red)[i] = 0.0f;
    if (t < 16) redlq[t] = 0.0f;
    __syncthreads();

    // C/D layout: col = lane&15, row = (lane>>4)*4 + reg  [m89-verified]
#pragma unroll
    for (int reg = 0; reg < 4; reg++){
        int r = kq * 4 + reg;
        atomicAdd(&red[0][r][lr],      accX0[reg]);
        atomicAdd(&red[0][r][16 + lr], accX1[reg]);
        atomicAdd(&red[1][r][lr],      accS0[reg]);
        atomicAdd(&red[1][r][16 + lr], accS1[reg]);
    }
    if (lane < 16) atomicAdd(&redlq[lane], lqv);
    __syncthreads();

    for (int i = t; i < 1024; i += 256){
        int set = i >> 9, r = (i >> 5) & 15, c = i & 31;
        float v = ((float*)red)[i];
        float* dst = (set ? Sg : Xg) + ((size_t)b * NROWS + tile * 16 + r) * 32 + c;
        atomicAdd(dst, v);
    }
    if (t < 16) atomicAdd(&lqs[b * NROWS + tile * 16 + t], redlq[t]);
}

// ---- fused: cost matrix + Hungarian (JV, f64, faithful) + final losses ----
__global__ __launch_bounds__(64) void k_match(const float* __restrict__ cl, const int* __restrict__ gtc,
                                              const float* __restrict__ Xg, const float* __restrict__ Sg,
                                              const float* __restrict__ lqs, float* __restrict__ out){
    __shared__ double c[MG][NQ];
    __shared__ double u[MG + 1];
    __shared__ double v[NQ + 1];
    __shared__ double minv[NQ + 1];
    __shared__ int p[NQ + 1];
    __shared__ int way[NQ + 1];
    __shared__ int used[NQ + 1];
    int b = blockIdx.x, t = threadIdx.x;

    // phase 1: cost into LDS (c[m][q], transposed like the reference JV input)
    for (int q = t; q < NQ; q += 64){
        const float* lg = cl + ((size_t)b * NQ + q) * C1;
        float l0=lg[0],l1=lg[1],l2=lg[2],l3=lg[3],l4=lg[4],l5=lg[5],l6=lg[6];
        float mx = fmaxf(fmaxf(fmaxf(l0,l1),fmaxf(l2,l3)), fmaxf(fmaxf(l4,l5),l6));
        float e0=__expf(l0-mx),e1=__expf(l1-mx),e2=__expf(l2-mx),e3=__expf(l3-mx),
              e4=__expf(l4-mx),e5=__expf(l5-mx),e6=__expf(l6-mx);
        float inv = 1.0f / (e0+e1+e2+e3+e4+e5+e6);
        float lqv = lqs[b * NROWS + q];
        float psv = Sg[((size_t)b * NROWS + q) * 32 + 20];
#pragma unroll
        for (int m = 0; m < MG; m++){
            int cc = gtc[b * MG + m];
            float ec = (cc==0)?e0:(cc==1)?e1:(cc==2)?e2:(cc==3)?e3:(cc==4)?e4:e5;
            float Xv = Xg[((size_t)b * NROWS + q) * 32 + m];
            float Sv = Sg[((size_t)b * NROWS + q) * 32 + m];
            float ysm = Xg[((size_t)b * NROWS + 100) * 32 + m];
            float bce = -(Xv + lqv) * (1.0f / (float)HWPX);
            float dice = 1.0f - (2.0f * Sv + 1.0f) / (psv + ysm + 1.0f);
            c[m][q] = (double)(2.0f * (-ec * inv) + 5.0f * bce + 5.0f * dice);
        }
    }
    for (int j = t; j <= NQ; j += 64){ v[j] = 0.0; p[j] = 0; way[j] = 0; }
    if (t <= MG) u[t] = 0.0;
    __syncthreads();

    // phase 2: Jonker-Volgenant on c^T equivalent ([20 rows x 100 cols])
    const double INF = 1e18;
    for (int i = 1; i <= MG; i++){
        if (t == 0) p[0] = i;
        for (int j = t; j <= NQ; j += 64){ minv[j] = INF; used[j] = 0; }
        __syncthreads();
        int j0 = 0;
        while (true){
            if (t == 0) used[j0] = 1;
            __syncthreads();
            int i0 = p[j0];
            double du = u[i0];
            for (int j = t + 1; j <= NQ; j += 64){
                if (!used[j]){
                    double cand = c[i0 - 1][j - 1] - du - v[j];
                    if (cand < minv[j]){ minv[j] = cand; way[j] = j0; }
                }
            }
            __syncthreads();
            double best = INF; int bj = NQ + 1;
            for (int j = t + 1; j <= NQ; j += 64){
                double mv = used[j] ? INF : minv[j];
                if (mv < best || (mv == best && j < bj)){ best = mv; bj = j; }
            }
#pragma unroll
            for (int off = 32; off; off >>= 1){
                double ob = __shfl_xor(best, off);
                int    oj = __shfl_xor(bj, off);
                if (ob < best || (ob == best && oj < bj)){ best = ob; bj = oj; }
            }
            int j1 = bj;
            double delta = best;
            for (int j = t; j <= NQ; j += 64){
                if (used[j]){ u[p[j]] += delta; v[j] -= delta; }
                else        { minv[j] -= delta; }
            }
            __syncthreads();
            j0 = j1;
            if (p[j0] == 0) break;
        }
        if (t == 0){
            int jj = j0;
            while (jj){ int jn = way[jj]; p[jj] = p[jn]; jj = jn; }
        }
        __syncthreads();
    }

    // phase 3: losses. p[j]=row(1-based) matched to pred col j -> target directly.
    float wnll = 0.f, wsum = 0.f, bsum = 0.f, dsum = 0.f;
    for (int q = t; q < NQ; q += 64){
        int pi = p[q + 1];
        int tg = (pi != 0) ? gtc[b * MG + (pi - 1)] : NO_OBJ_C;
        const float* lg = cl + ((size_t)b * NQ + q) * C1;
        float l0=lg[0],l1=lg[1],l2=lg[2],l3=lg[3],l4=lg[4],l5=lg[5],l6=lg[6];
        float mx = fmaxf(fmaxf(fmaxf(l0,l1),fmaxf(l2,l3)), fmaxf(fmaxf(l4,l5),l6));
        float se = __expf(l0-mx)+__expf(l1-mx)+__expf(l2-mx)+__expf(l3-mx)
                 + __expf(l4-mx)+__expf(l5-mx)+__expf(l6-mx);
        float lse = __logf(se) + mx;
        float lt = (tg==0)?l0:(tg==1)?l1:(tg==2)?l2:(tg==3)?l3:(tg==4)?l4:(tg==5)?l5:l6;
        float w = (tg == NO_OBJ_C) ? 0.1f : 1.0f;
        wnll += w * (lse - lt);
        wsum += w;
        if (pi != 0){
            int k = pi - 1;
            float Xv  = Xg[((size_t)b * NROWS + q) * 32 + k];
            float Sv  = Sg[((size_t)b * NROWS + q) * 32 + k];
            float lqv = lqs[b * NROWS + q];
            float psv = Sg[((size_t)b * NROWS + q) * 32 + 20];
            float ysm = Xg[((size_t)b * NROWS + 100) * 32 + k];
            bsum += -(Xv + lqv);
            dsum += 1.0f - (2.0f * Sv + 1.0f) / (psv + ysm + 1.0f);
        }
    }
#pragma unroll
    for (int off = 32; off; off >>= 1){
        wnll += __shfl_xor(wnll, off);
        wsum += __shfl_xor(wsum, off);
        bsum += __shfl_xor(bsum, off);
        dsum += __shfl_xor(dsum, off);
    }
    if (t == 0){
        float tc = wnll / wsum;
        float tm = bsum / ((float)MG * (float)HWPX);
        float td = dsum / (float)MG;
        atomicAdd(&out[0], 0.5f * tc);
        atomicAdd(&out[1], 0.5f * tm);
        atomicAdd(&out[2], 0.5f * td);
        atomicAdd(&out[3], 0.5f * (2.0f * tc + 5.0f * tm + 5.0f * td));
    }
}

extern "C" void kernel_launch(void* const* d_in, const int* in_sizes, int n_in,
                              void* d_out, int out_size, void* d_ws, size_t ws_size,
                              hipStream_t stream){
    const float* cls_logits  = (const float*)d_in[0];
    const float* mask_logits = (const float*)d_in[1];
    const int*   gt_classes  = (const int*)d_in[2];
    const int*   gt_masks    = (const int*)d_in[3];
    float* out = (float*)d_out;
    char* ws = (char*)d_ws;

    u32*   packed = (u32*)  (ws + OFF_PACKED);
    float* Xg     = (float*)(ws + OFF_X);
    float* Sg     = (float*)(ws + OFF_S);
    float* lqs    = (float*)(ws + OFF_LQS);

    (void)hipMemsetAsync(ws + OFF_X, 0, ZERO_BYTES, stream);
    hipLaunchKernelGGL(k_pack,  dim3(BS * HWPX / 1024),      dim3(256), 0, stream, gt_masks, packed, out);
    hipLaunchKernelGGL(k_main,  dim3(BS * NCHUNK * NT),      dim3(256), 0, stream, mask_logits, packed, Xg, Sg, lqs);
    hipLaunchKernelGGL(k_match, dim3(BS),                    dim3(64),  0, stream, cls_logits, gt_classes, Xg, Sg, lqs, out);
}

// Round 4
// 167.610 us; speedup vs baseline: 2.7034x; 1.0204x over previous
//
#include <hip/hip_runtime.h>

// EoMT criterion v3: MFMA-based mask reductions + fused cost/Hungarian/losses.
// v3: remove in-graph hipMemsetAsync (rocclr small-fill kernel cost 120us/iter!);
//     zero accumulators from k_pack block 0 instead.
// Shapes fixed: bs=2, N=100, C+1=7, H=W=512 (HW=262144), M=20.

typedef unsigned int u32;
typedef __attribute__((ext_vector_type(8))) short short8;   // 8 bf16 (4 VGPRs)
typedef __attribute__((ext_vector_type(4))) float f32x4;

#define BS 2
#define NQ 100
#define C1 7
#define HWPX 262144
#define MG 20
#define NO_OBJ_C 6
#define NROWS 112            // 7 tiles of 16: rows 0-99 real, 100-111 = ones rows (row100 -> ysum)
#define NT 7
#define CHUNK 2048           // pixels per block
#define NCHUNK (HWPX / CHUNK)   // 128
#define WSUB (CHUNK / 4)     // 512 px per wave
#define KSTEPS (WSUB / 32)   // 16

// ---- workspace layout (bytes) ----
static constexpr size_t OFF_PACKED = 0;                                 // u32 [BS][HWPX] = 2MB
static constexpr size_t OFF_X      = (size_t)BS * HWPX * 4;             // f32 [BS][112][32]
static constexpr size_t OFF_S      = OFF_X + (size_t)BS * NROWS * 32 * 4;
static constexpr size_t OFF_LQS    = OFF_S + (size_t)BS * NROWS * 32 * 4; // f32 [BS][112]
static constexpr size_t ZERO_BYTES = (OFF_LQS + (size_t)BS * NROWS * 4) - OFF_X;  // 58240 B

__device__ __forceinline__ float fast_rcp(float x){
#if __has_builtin(__builtin_amdgcn_rcpf)
    return __builtin_amdgcn_rcpf(x);
#else
    return 1.0f / x;
#endif
}

__device__ __forceinline__ short8 mk8(const u32 w[4]){
    union { u32 u[4]; short8 v; } c;
    c.u[0] = w[0]; c.u[1] = w[1]; c.u[2] = w[2]; c.u[3] = w[3];
    return c.v;
}

// f32 -> bf16 bits, round-to-nearest-even (inputs are finite; no NaN handling needed)
__device__ __forceinline__ u32 f2bf(float f){
    u32 u = __builtin_bit_cast(u32, f);
    return (u + 0x7FFFu + ((u >> 16) & 1u)) >> 16;
}
__device__ __forceinline__ u32 pkbf(float lo, float hi){
    return f2bf(lo) | (f2bf(hi) << 16);
}

// ---- pack 20 binary masks into one u32 per pixel (4 px/thread) + zero accumulators/out ----
__global__ __launch_bounds__(256) void k_pack(const int* __restrict__ gt, u32* __restrict__ packed,
                                              float* __restrict__ accum /* = ws+OFF_X */,
                                              float* __restrict__ out){
    if (blockIdx.x == 0){
        // zero X/S/lqs region (58240 B = 3640 float4) + d_out
        f32x4 z = {0.f, 0.f, 0.f, 0.f};
        f32x4* a4 = (f32x4*)accum;
        for (int i = threadIdx.x; i < (int)(ZERO_BYTES / 16); i += 256) a4[i] = z;
        if (threadIdx.x < 4) out[threadIdx.x] = 0.0f;
    }
    int i4 = blockIdx.x * 256 + threadIdx.x;      // 0 .. BS*HWPX/4-1
    int base = i4 * 4;
    int b = base >> 18;
    int pix = base & (HWPX - 1);
    const int* g = gt + ((size_t)b * MG << 18) + pix;
    u32 w0 = 0, w1 = 0, w2 = 0, w3 = 0;
#pragma unroll
    for (int m = 0; m < MG; m++){
        int4 v = *(const int4*)(g + ((size_t)m << 18));
        w0 |= ((u32)v.x & 1u) << m;
        w1 |= ((u32)v.y & 1u) << m;
        w2 |= ((u32)v.z & 1u) << m;
        w3 |= ((u32)v.w & 1u) << m;
    }
    *(uint4*)(packed + ((size_t)b << 18) + pix) = make_uint4(w0, w1, w2, w3);
}

// ---- heavy kernel: X[n,m], S[n,m] via MFMA; lqsum via VALU; psum via ones-col; ysum via ones-rows ----
__global__ __launch_bounds__(256) void k_main(const float* __restrict__ mlog, const u32* __restrict__ pkd,
                                              float* __restrict__ Xg, float* __restrict__ Sg,
                                              float* __restrict__ lqs){
    int blk = blockIdx.x;                 // [BS * NCHUNK * NT]
    int tile = blk % NT;
    int rest = blk / NT;
    int chunk = rest % NCHUNK;
    int b = rest / NCHUNK;
    int t = threadIdx.x;
    int wave = t >> 6, lane = t & 63;
    int lr = lane & 15;                   // A-row-in-tile / B-col
    int kq = lane >> 4;                   // k-quarter
    int row = tile * 16 + lr;             // global n row (0..111)
    bool real = row < NQ;
    int rowc = real ? row : (NQ - 1);

    const float* xrow = mlog + ((size_t)b * NQ + rowc) * HWPX;
    const u32* pk = pkd + ((size_t)b << 18);
    int pxbase = chunk * CHUNK + wave * WSUB + kq * 8;

    // B-expansion per-lane constants
    u32 bsel1 = 1u << lr;                               // tile1: mask bit lr
    u32 bsel2 = (lr < 4) ? (0x10000u << lr) : 0u;       // tile2: masks 16..19
    u32 bforce = (lr == 4) ? 0x3F80u : 0u;              // tile2 col 20 = ones

    f32x4 accX0 = {0,0,0,0}, accX1 = {0,0,0,0}, accS0 = {0,0,0,0}, accS1 = {0,0,0,0};
    float lqacc = 0.0f;

#pragma unroll 2
    for (int s = 0; s < KSTEPS; s++){
        int px = pxbase + s * 32;
        f32x4 xa = *(const f32x4*)(xrow + px);
        f32x4 xb = *(const f32x4*)(xrow + px + 4);
        uint4 wa = *(const uint4*)(pk + px);
        uint4 wb = *(const uint4*)(pk + px + 4);
        u32 w[8]  = {wa.x, wa.y, wa.z, wa.w, wb.x, wb.y, wb.z, wb.w};
        float x[8] = {xa[0], xa[1], xa[2], xa[3], xb[0], xb[1], xb[2], xb[3]};

        u32 axw[4], apw[4], b1w[4], b2w[4];
#pragma unroll
        for (int jj = 0; jj < 4; jj++){
            float x0 = x[2*jj], x1 = x[2*jj+1];
            float e0 = __expf(-x0), e1 = __expf(-x1);
            float d0 = 1.0f + e0,   d1 = 1.0f + e1;
            float p0 = fast_rcp(d0), p1 = fast_rcp(d1);
            float lq0 = -__logf(d0) - x0;      // log(1 - sigmoid(x))
            float lq1 = -__logf(d1) - x1;
            lqacc += lq0 + lq1;
            axw[jj] = pkbf(x0, x1);
            apw[jj] = pkbf(p0, p1);
            u32 wl = w[2*jj], wh = w[2*jj+1];
            u32 t1l = (wl & bsel1) ? 0x3F80u : 0u;
            u32 t1h = (wh & bsel1) ? 0x3F80u : 0u;
            u32 t2l = ((wl & bsel2) ? 0x3F80u : 0u) | bforce;
            u32 t2h = ((wh & bsel2) ? 0x3F80u : 0u) | bforce;
            b1w[jj] = t1l | (t1h << 16);
            b2w[jj] = t2l | (t2h << 16);
        }
        if (!real){
#pragma unroll
            for (int jj = 0; jj < 4; jj++){ axw[jj] = 0x3F803F80u; apw[jj] = 0x3F803F80u; }
        }
        short8 Ax = mk8(axw), Ap = mk8(apw), B0 = mk8(b1w), B1 = mk8(b2w);
        accX0 = __builtin_amdgcn_mfma_f32_16x16x32_bf16(Ax, B0, accX0, 0, 0, 0);
        accX1 = __builtin_amdgcn_mfma_f32_16x16x32_bf16(Ax, B1, accX1, 0, 0, 0);
        accS0 = __builtin_amdgcn_mfma_f32_16x16x32_bf16(Ap, B0, accS0, 0, 0, 0);
        accS1 = __builtin_amdgcn_mfma_f32_16x16x32_bf16(Ap, B1, accS1, 0, 0, 0);
    }

    // lq: rows live on lanes (lr, lr+16, lr+32, lr+48) -> combine quarters
    float lqv = lqacc + __shfl_xor(lqacc, 16);
    lqv += __shfl_xor(lqv, 32);

    __shared__ float red[2][16][32];
    __shared__ float redlq[16];
    for (int i = t; i < 2*16*32; i += 256) ((float*)red)[i] = 0.0f;
    if (t < 16) redlq[t] = 0.0f;
    __syncthreads();

    // C/D layout: col = lane&15, row = (lane>>4)*4 + reg  [m89-verified]
#pragma unroll
    for (int reg = 0; reg < 4; reg++){
        int r = kq * 4 + reg;
        atomicAdd(&red[0][r][lr],      accX0[reg]);
        atomicAdd(&red[0][r][16 + lr], accX1[reg]);
        atomicAdd(&red[1][r][lr],      accS0[reg]);
        atomicAdd(&red[1][r][16 + lr], accS1[reg]);
    }
    if (lane < 16) atomicAdd(&redlq[lane], lqv);
    __syncthreads();

    for (int i = t; i < 1024; i += 256){
        int set = i >> 9, r = (i >> 5) & 15, c = i & 31;
        float v = ((float*)red)[i];
        float* dst = (set ? Sg : Xg) + ((size_t)b * NROWS + tile * 16 + r) * 32 + c;
        atomicAdd(dst, v);
    }
    if (t < 16) atomicAdd(&lqs[b * NROWS + tile * 16 + t], redlq[t]);
}

// ---- fused: cost matrix + Hungarian (JV, f64, faithful) + final losses ----
__global__ __launch_bounds__(64) void k_match(const float* __restrict__ cl, const int* __restrict__ gtc,
                                              const float* __restrict__ Xg, const float* __restrict__ Sg,
                                              const float* __restrict__ lqs, float* __restrict__ out){
    __shared__ double c[MG][NQ];
    __shared__ double u[MG + 1];
    __shared__ double v[NQ + 1];
    __shared__ double minv[NQ + 1];
    __shared__ int p[NQ + 1];
    __shared__ int way[NQ + 1];
    __shared__ int used[NQ + 1];
    int b = blockIdx.x, t = threadIdx.x;

    // phase 1: cost into LDS (c[m][q], transposed like the reference JV input)
    for (int q = t; q < NQ; q += 64){
        const float* lg = cl + ((size_t)b * NQ + q) * C1;
        float l0=lg[0],l1=lg[1],l2=lg[2],l3=lg[3],l4=lg[4],l5=lg[5],l6=lg[6];
        float mx = fmaxf(fmaxf(fmaxf(l0,l1),fmaxf(l2,l3)), fmaxf(fmaxf(l4,l5),l6));
        float e0=__expf(l0-mx),e1=__expf(l1-mx),e2=__expf(l2-mx),e3=__expf(l3-mx),
              e4=__expf(l4-mx),e5=__expf(l5-mx),e6=__expf(l6-mx);
        float inv = 1.0f / (e0+e1+e2+e3+e4+e5+e6);
        float lqv = lqs[b * NROWS + q];
        float psv = Sg[((size_t)b * NROWS + q) * 32 + 20];
#pragma unroll
        for (int m = 0; m < MG; m++){
            int cc = gtc[b * MG + m];
            float ec = (cc==0)?e0:(cc==1)?e1:(cc==2)?e2:(cc==3)?e3:(cc==4)?e4:e5;
            float Xv = Xg[((size_t)b * NROWS + q) * 32 + m];
            float Sv = Sg[((size_t)b * NROWS + q) * 32 + m];
            float ysm = Xg[((size_t)b * NROWS + 100) * 32 + m];
            float bce = -(Xv + lqv) * (1.0f / (float)HWPX);
            float dice = 1.0f - (2.0f * Sv + 1.0f) / (psv + ysm + 1.0f);
            c[m][q] = (double)(2.0f * (-ec * inv) + 5.0f * bce + 5.0f * dice);
        }
    }
    for (int j = t; j <= NQ; j += 64){ v[j] = 0.0; p[j] = 0; way[j] = 0; }
    if (t <= MG) u[t] = 0.0;
    __syncthreads();

    // phase 2: Jonker-Volgenant on c^T equivalent ([20 rows x 100 cols])
    const double INF = 1e18;
    for (int i = 1; i <= MG; i++){
        if (t == 0) p[0] = i;
        for (int j = t; j <= NQ; j += 64){ minv[j] = INF; used[j] = 0; }
        __syncthreads();
        int j0 = 0;
        while (true){
            if (t == 0) used[j0] = 1;
            __syncthreads();
            int i0 = p[j0];
            double du = u[i0];
            for (int j = t + 1; j <= NQ; j += 64){
                if (!used[j]){
                    double cand = c[i0 - 1][j - 1] - du - v[j];
                    if (cand < minv[j]){ minv[j] = cand; way[j] = j0; }
                }
            }
            __syncthreads();
            double best = INF; int bj = NQ + 1;
            for (int j = t + 1; j <= NQ; j += 64){
                double mv = used[j] ? INF : minv[j];
                if (mv < best || (mv == best && j < bj)){ best = mv; bj = j; }
            }
#pragma unroll
            for (int off = 32; off; off >>= 1){
                double ob = __shfl_xor(best, off);
                int    oj = __shfl_xor(bj, off);
                if (ob < best || (ob == best && oj < bj)){ best = ob; bj = oj; }
            }
            int j1 = bj;
            double delta = best;
            for (int j = t; j <= NQ; j += 64){
                if (used[j]){ u[p[j]] += delta; v[j] -= delta; }
                else        { minv[j] -= delta; }
            }
            __syncthreads();
            j0 = j1;
            if (p[j0] == 0) break;
        }
        if (t == 0){
            int jj = j0;
            while (jj){ int jn = way[jj]; p[jj] = p[jn]; jj = jn; }
        }
        __syncthreads();
    }

    // phase 3: losses. p[j]=row(1-based) matched to pred col j -> target directly.
    float wnll = 0.f, wsum = 0.f, bsum = 0.f, dsum = 0.f;
    for (int q = t; q < NQ; q += 64){
        int pi = p[q + 1];
        int tg = (pi != 0) ? gtc[b * MG + (pi - 1)] : NO_OBJ_C;
        const float* lg = cl + ((size_t)b * NQ + q) * C1;
        float l0=lg[0],l1=lg[1],l2=lg[2],l3=lg[3],l4=lg[4],l5=lg[5],l6=lg[6];
        float mx = fmaxf(fmaxf(fmaxf(l0,l1),fmaxf(l2,l3)), fmaxf(fmaxf(l4,l5),l6));
        float se = __expf(l0-mx)+__expf(l1-mx)+__expf(l2-mx)+__expf(l3-mx)
                 + __expf(l4-mx)+__expf(l5-mx)+__expf(l6-mx);
        float lse = __logf(se) + mx;
        float lt = (tg==0)?l0:(tg==1)?l1:(tg==2)?l2:(tg==3)?l3:(tg==4)?l4:(tg==5)?l5:l6;
        float w = (tg == NO_OBJ_C) ? 0.1f : 1.0f;
        wnll += w * (lse - lt);
        wsum += w;
        if (pi != 0){
            int k = pi - 1;
            float Xv  = Xg[((size_t)b * NROWS + q) * 32 + k];
            float Sv  = Sg[((size_t)b * NROWS + q) * 32 + k];
            float lqv = lqs[b * NROWS + q];
            float psv = Sg[((size_t)b * NROWS + q) * 32 + 20];
            float ysm = Xg[((size_t)b * NROWS + 100) * 32 + k];
            bsum += -(Xv + lqv);
            dsum += 1.0f - (2.0f * Sv + 1.0f) / (psv + ysm + 1.0f);
        }
    }
#pragma unroll
    for (int off = 32; off; off >>= 1){
        wnll += __shfl_xor(wnll, off);
        wsum += __shfl_xor(wsum, off);
        bsum += __shfl_xor(bsum, off);
        dsum += __shfl_xor(dsum, off);
    }
    if (t == 0){
        float tc = wnll / wsum;
        float tm = bsum / ((float)MG * (float)HWPX);
        float td = dsum / (float)MG;
        atomicAdd(&out[0], 0.5f * tc);
        atomicAdd(&out[1], 0.5f * tm);
        atomicAdd(&out[2], 0.5f * td);
        atomicAdd(&out[3], 0.5f * (2.0f * tc + 5.0f * tm + 5.0f * td));
    }
}

extern "C" void kernel_launch(void* const* d_in, const int* in_sizes, int n_in,
                              void* d_out, int out_size, void* d_ws, size_t ws_size,
                              hipStream_t stream){
    const float* cls_logits  = (const float*)d_in[0];
    const float* mask_logits = (const float*)d_in[1];
    const int*   gt_classes  = (const int*)d_in[2];
    const int*   gt_masks    = (const int*)d_in[3];
    float* out = (float*)d_out;
    char* ws = (char*)d_ws;

    u32*   packed = (u32*)  (ws + OFF_PACKED);
    float* Xg     = (float*)(ws + OFF_X);
    float* Sg     = (float*)(ws + OFF_S);
    float* lqs    = (float*)(ws + OFF_LQS);

    hipLaunchKernelGGL(k_pack,  dim3(BS * HWPX / 1024),      dim3(256), 0, stream, gt_masks, packed, Xg, out);
    hipLaunchKernelGGL(k_main,  dim3(BS * NCHUNK * NT),      dim3(256), 0, stream, mask_logits, packed, Xg, Sg, lqs);
    hipLaunchKernelGGL(k_match, dim3(BS),                    dim3(64),  0, stream, cls_logits, gt_classes, Xg, Sg, lqs, out);
}